// Round 22
// baseline (262.714 us; speedup 1.0000x reference)
//
#include <hip/hip_runtime.h>
#include <math.h>

typedef float f32x4 __attribute__((ext_vector_type(4)));
typedef short bf16x8 __attribute__((ext_vector_type(8)));
typedef short s16x4 __attribute__((ext_vector_type(4)));

#define BB 16
#define LL 8192
#define DIN 128
#define HH 256
#define NCH 32
#define TCH 256

// ---------------- workspace layout (byte offsets) ----------------
#define U_OFF    0ull            // u/y bf16 (B,H,L) 67108864
#define PRM_OFF  67108864ull     // prm fp32 8 planes x 8192
#define KK_OFF   67371008ull     // [unused]
#define WKE_OFF  67633152ull     // WKE bf16 FRAGMENT-ORDER (256h x 40q x 256m x 8c) 41943040
#define F_OFF    109576192ull    // F bf16 (256h,64,256) 8388608
#define SB_OFF   117964800ull    // [unused]
#define SBH_OFF  134742016ull    // s_in  bf16 (B,H,32,64) 16777216
#define W1T_OFF  151519232ull    // W1 fragment-ordered bf16 (16,256,8)
#define WOT_OFF  151584768ull    // Wo^T bf16 (512,256)
#define PART_OFF 151846912ull    // part fp32 (B,64,256)
#define POOL_OFF 152895488ull
#define FC_OFF   152911872ull

static __device__ __forceinline__ unsigned short f2b(float f){
  unsigned int u = __float_as_uint(f);
  return (unsigned short)((u + 0x7fffu + ((u>>16)&1u)) >> 16);
}
static __device__ __forceinline__ float b2f(unsigned int h){
  return __uint_as_float((h & 0xffffu)<<16);
}

// tanh-approx GELU: v * sigmoid(2*sqrt(2/pi)*(v + 0.044715 v^3))
static __device__ __forceinline__ float gelu_t(float v){
  float vv = v*v;
  float p  = fmaf(0.044715f, vv, 1.0f);
  float z  = v*p*(-1.5957691216057308f);
  float e  = __expf(z);
  return v*__builtin_amdgcn_rcpf(1.0f + e);
}

// async global->LDS, 16B per lane; LDS dest must be wave-uniform base (HW adds lane*16)
typedef __attribute__((address_space(3))) unsigned int lds_u32_t;
typedef __attribute__((address_space(3))) unsigned short lds_u16_t;
typedef const __attribute__((address_space(1))) unsigned int glb_u32_t;
static __device__ __forceinline__ void gl16(const void* g, void* l){
  __builtin_amdgcn_global_load_lds((glb_u32_t*)g, (lds_u32_t*)l, 16, 0, 0);
}

// ---------------- KP_ALL: fused independent prologue ----------------
// ranges: [0,32) k0-prm | [32,544) kw_wot | [544,672) kw_w1t |
//         [672,2720) E (parallel, fragment layout) | [2720,10912) F (parallel)
__global__ __launch_bounds__(256) void kp_all(
    const float* __restrict__ log_dt, const float* __restrict__ log_A_real,
    const float* __restrict__ A_imag, const float* __restrict__ C_re,
    const float* __restrict__ C_im, float* __restrict__ prm,
    const float* __restrict__ Wo, unsigned short* __restrict__ wot,
    const float* __restrict__ W1, unsigned short* __restrict__ w1t,
    unsigned short* __restrict__ wke, unsigned short* __restrict__ fb){
  int bid = blockIdx.x;
  int t = threadIdx.x;
  if (bid < 32){
    // ---- k0: S4D discretized parameters (prm planes; scan needs aT) ----
    int id = bid*256 + t;
    int h = id >> 5;
    float dt = expf(log_dt[h]);
    float Ar = -expf(log_A_real[id]);
    float Ai = A_imag[id];
    float dr = Ar*dt, di = Ai*dt;
    float ear = expf(dr);
    float are = ear*cosf(di), aim = ear*sinf(di);
    float er = are - 1.0f, ei = aim;
    float den = 1.0f/(Ar*Ar + Ai*Ai);
    float Br = (er*Ar + ei*Ai)*den;
    float Bi = (ei*Ar - er*Ai)*den;
    float c_r = C_re[id], c_i = C_im[id];
    float cre = 2.0f*(c_r*Br - c_i*Bi);
    float cim = 2.0f*(c_r*Bi + c_i*Br);
    double phi = (double)di*(double)TCH;
    float eT = expf(dr*(float)TCH);
    float aTre = eT*(float)cos(phi);
    float aTim = eT*(float)sin(phi);
    prm[id]         = are;  prm[8192  + id] = aim;
    prm[16384 + id] = cre;  prm[24576 + id] = cim;
    prm[32768 + id] = aTre; prm[40960 + id] = aTim;
    prm[49152 + id] = dr;   prm[57344 + id] = di;
  } else if (bid < 544){
    // ---- kw_wot ----
    int id = (bid-32)*256 + t;        // 131072
    int k = id >> 9, n = id & 511;
    wot[n*256 + k] = f2b(Wo[id]);
  } else if (bid < 672){
    // ---- kw_w1t (fragment order) ----
    int id = (bid-544)*256 + t;       // 32768
    int k = id >> 8, n = id & 255;
    w1t[((k>>3)<<11) + (n<<3) + (k&7)] = f2b(W1[k*256 + n]);
  } else if (bid < 2720){
    // ---- E into WKE fragment layout, computed per-element (a^{m+1}) ----
    int bid2 = bid - 672;             // 2048 = (h, ngroup)
    int h = bid2 >> 3, ng = bid2 & 7;
    int nn = t & 3;                   // n within group
    int n  = (ng<<2) + nn;
    int hn = (h<<5) + n;
    float dt = expf(log_dt[h]);
    float Ar = -expf(log_A_real[hn]);
    float Ai = A_imag[hn];
    float dr = Ar*dt, di = Ai*dt;
    float ear = expf(dr);
    float are = ear*cosf(di), aim = ear*sinf(di);
    float er = are - 1.0f, ei = aim;
    float den = 1.0f/(Ar*Ar + Ai*Ai);
    float Br = (er*Ar + ei*Ai)*den;
    float Bi = (ei*Ar - er*Ai)*den;
    float c_r = C_re[hn], c_i = C_im[hn];
    float cre = 2.0f*(c_r*Br - c_i*Bi);
    float cim = 2.0f*(c_r*Bi + c_i*Br);
    int q = 32 + ng, c = nn << 1;
    unsigned short* W = wke + (size_t)h*81920 + ((size_t)q<<11) + c;
    int mb = t >> 2;
    #pragma unroll
    for (int i = 0; i < 4; ++i){
      int m = mb + (i<<6);
      float fm = (float)(m+1);
      float E  = expf(dr*fm);
      float ph = di*fm;
      float car = E*cosf(ph), sar = E*sinf(ph);
      float zr = cre*car - cim*sar;
      float zi = cre*sar + cim*car;
      *(unsigned int*)(W + (m<<3)) = ((unsigned int)f2b(-zi)<<16) | f2b(zr);
    }
  } else {
    // ---- F per-element: Fh[j] = a^{255-j} ----
    int bid3 = bid - 2720;            // 8192 = (h,n)
    int h = bid3 >> 5, n = bid3 & 31;
    int hn = (h<<5) + n;
    float dt = expf(log_dt[h]);
    float Ar = -expf(log_A_real[hn]);
    float Ai = A_imag[hn];
    float dr = Ar*dt, di = Ai*dt;
    int j = t;
    float fp = (float)(255 - j);
    float E  = expf(dr*fp);
    float ph = di*fp;
    unsigned short* Fh = fb + ((size_t)h<<14) + (n<<9);
    Fh[j]       = f2b(E*cosf(ph));
    Fh[256 + j] = f2b(E*sinf(ph));
  }
}

// ---------------- KP_KHW: fused kernel-taps + Toeplitz WKE (per head) ----------------
__global__ __launch_bounds__(256) void kp_khw(const float* __restrict__ prm,
                                              const float* __restrict__ Dp,
                                              unsigned short* __restrict__ wke){
  __shared__ float kh[256];
  int h = blockIdx.x;
  int d = threadIdx.x;
  {
    float fd = (float)d;
    float s = 0.f;
    #pragma unroll 8
    for (int n = 0; n < 32; ++n){
      int i0 = (h<<5) + n;
      float dr = prm[49152 + i0], di = prm[57344 + i0];
      float cr = prm[16384 + i0], ci = prm[24576 + i0];
      float e = expf(dr*fd);
      float ph = di*fd;
      s += e*(cr*cosf(ph) - ci*sinf(ph));
    }
    kh[d] = s;
  }
  __syncthreads();
  int m = threadIdx.x;
  float dp = Dp[h];
  unsigned short* W = wke + (size_t)h*81920;
  for (int j4 = 0; j4 < 256; j4 += 4){
    ushort4 o;
    float v0 = (j4+0 <= m) ? kh[m-j4-0] : 0.f; if (j4+0 == m) v0 += dp;
    float v1 = (j4+1 <= m) ? kh[m-j4-1] : 0.f; if (j4+1 == m) v1 += dp;
    float v2 = (j4+2 <= m) ? kh[m-j4-2] : 0.f; if (j4+2 == m) v2 += dp;
    float v3 = (j4+3 <= m) ? kh[m-j4-3] : 0.f; if (j4+3 == m) v3 += dp;
    o.x = f2b(v0); o.y = f2b(v1); o.z = f2b(v2); o.w = f2b(v3);
    *(ushort4*)(W + (((j4>>3)<<11)) + (m<<3) + (j4&7)) = o;
  }
}

// ---------------- K1: fc1 + ReLU + LayerNorm (MFMA) -> u bf16 (B,H,L) ----------------
__global__ __launch_bounds__(512, 4) void k1_fc1_ln(const float* __restrict__ x,
    const unsigned short* __restrict__ w1t, const float* __restrict__ b1,
    const float* __restrict__ lng, const float* __restrict__ lnb,
    unsigned short* __restrict__ u){
  __shared__ unsigned short sX[64*128];
  __shared__ float sRed[4][64][2];
  int t = threadIdx.x;
  int lane = t & 63, wid = t >> 6;
  int wr = wid >> 2, wc = wid & 3;
  int g0 = blockIdx.x << 6;
  int b = g0 >> 13, l0 = g0 & 8191;
  {
    int r = t >> 3, kq = (t & 7) << 4;
    const float* xr = x + (size_t)(g0 + r)*DIN + kq;
    #pragma unroll
    for (int i = 0; i < 4; ++i){
      float4 v = *(const float4*)(xr + i*4);
      ushort4 o; o.x=f2b(v.x); o.y=f2b(v.y); o.z=f2b(v.z); o.w=f2b(v.w);
      int k0 = kq + i*4;
      int q = k0 >> 3;
      *(ushort4*)&sX[(r<<7) + ((q ^ (r&7))<<3) + (k0&7)] = o;
    }
  }
  __syncthreads();
  f32x4 acc[2][4];
  #pragma unroll
  for (int mi = 0; mi < 2; ++mi)
    #pragma unroll
    for (int ni = 0; ni < 4; ++ni) acc[mi][ni] = (f32x4){0.f,0.f,0.f,0.f};
  #pragma unroll
  for (int kt = 0; kt < 4; ++kt){
    bf16x8 af[2];
    #pragma unroll
    for (int mi = 0; mi < 2; ++mi){
      int m = (wr<<5) + (mi<<4) + (lane&15);
      int q = (kt<<2) + (lane>>4);
      af[mi] = *(const bf16x8*)&sX[(m<<7) + ((q ^ (m&7))<<3)];
    }
    #pragma unroll
    for (int ni = 0; ni < 4; ++ni){
      int hcol = (wc<<6) + (ni<<4) + (lane&15);
      bf16x8 bf = *(const bf16x8*)(w1t + (((kt<<2) + (lane>>4))<<11) + (hcol<<3));
      acc[0][ni] = __builtin_amdgcn_mfma_f32_16x16x32_bf16(af[0], bf, acc[0][ni], 0,0,0);
      acc[1][ni] = __builtin_amdgcn_mfma_f32_16x16x32_bf16(af[1], bf, acc[1][ni], 0,0,0);
    }
  }
  float bv[4];
  #pragma unroll
  for (int ni = 0; ni < 4; ++ni) bv[ni] = b1[(wc<<6) + (ni<<4) + (lane&15)];
  float s1[2][4] = {{0,0,0,0},{0,0,0,0}}, s2[2][4] = {{0,0,0,0},{0,0,0,0}};
  #pragma unroll
  for (int mi = 0; mi < 2; ++mi)
    #pragma unroll
    for (int ni = 0; ni < 4; ++ni)
      #pragma unroll
      for (int rr = 0; rr < 4; ++rr){
        float v = acc[mi][ni][rr] + bv[ni];
        v = v > 0.f ? v : 0.f;
        acc[mi][ni][rr] = v;
        s1[mi][rr] += v; s2[mi][rr] = fmaf(v, v, s2[mi][rr]);
      }
  #pragma unroll
  for (int off = 1; off < 16; off <<= 1)
    #pragma unroll
    for (int mi = 0; mi < 2; ++mi)
      #pragma unroll
      for (int rr = 0; rr < 4; ++rr){
        s1[mi][rr] += __shfl_xor(s1[mi][rr], off);
        s2[mi][rr] += __shfl_xor(s2[mi][rr], off);
      }
  if ((lane & 15) == 0){
    #pragma unroll
    for (int mi = 0; mi < 2; ++mi)
      #pragma unroll
      for (int rr = 0; rr < 4; ++rr){
        int row = (wr<<5) + (mi<<4) + ((lane>>4)<<2) + rr;
        sRed[wc][row][0] = s1[mi][rr];
        sRed[wc][row][1] = s2[mi][rr];
      }
  }
  __syncthreads();
  float mu[2][4], rs[2][4];
  #pragma unroll
  for (int mi = 0; mi < 2; ++mi)
    #pragma unroll
    for (int rr = 0; rr < 4; ++rr){
      int row = (wr<<5) + (mi<<4) + ((lane>>4)<<2) + rr;
      float t1 = sRed[0][row][0] + sRed[1][row][0] + sRed[2][row][0] + sRed[3][row][0];
      float t2 = sRed[0][row][1] + sRed[1][row][1] + sRed[2][row][1] + sRed[3][row][1];
      float m_ = t1*(1.f/256.f);
      mu[mi][rr] = m_;
      rs[mi][rr] = rsqrtf(t2*(1.f/256.f) - m_*m_ + 1e-5f);
    }
  #pragma unroll
  for (int ni = 0; ni < 4; ++ni){
    int hcol = (wc<<6) + (ni<<4) + (lane&15);
    float g = lng[hcol], bb = lnb[hcol];
    #pragma unroll
    for (int mi = 0; mi < 2; ++mi){
      ushort4 o;
      o.x = f2b((acc[mi][ni][0]-mu[mi][0])*rs[mi][0]*g + bb);
      o.y = f2b((acc[mi][ni][1]-mu[mi][1])*rs[mi][1]*g + bb);
      o.z = f2b((acc[mi][ni][2]-mu[mi][2])*rs[mi][2]*g + bb);
      o.w = f2b((acc[mi][ni][3]-mu[mi][3])*rs[mi][3]*g + bb);
      *(ushort4*)(u + (((size_t)(b*HH + hcol))<<13) + l0 + (wr<<5) + (mi<<4) + ((lane>>4)<<2)) = o;
    }
  }
}

// ---------------- K2a: s_loc = F * u  + FUSED chunk-prefix scan -> sbh ----------------
__global__ __launch_bounds__(256, 4) void k2a_states(const unsigned short* __restrict__ u,
                                                     const unsigned short* __restrict__ fb,
                                                     const float* __restrict__ prm,
                                                     unsigned short* __restrict__ sbh){
  __shared__ unsigned short sA2[2][64*32];    // 2 x 4 KB
  __shared__ unsigned short sB2[2][128*32];   // 2 x 8 KB
  __shared__ unsigned short sS[128*64];       // s_loc [col][row] 16 KB
  int bid = blockIdx.x;
  int lb = ((bid & 7) << 7) + (bid >> 3);   // 1024 = 8*128, XCD chunking
  int h = lb >> 2, nt = lb & 3;
  int t = threadIdx.x;
  int lane = t & 63, wid = t >> 6;
  int wr = wid >> 1, wc = wid & 1;

  // A staging: chunk c=t -> row t>>2 (0..63), slot t&3; source pre-swizzled
  int ar0 = t >> 2;
  int asl = t & 3;
  int asw = (asl ^ ((ar0 >> 1) & 3)) << 3;
  const unsigned short* aS = fb + ((size_t)h<<14) + ar0*256 + asw;

  // B staging: chunks c=t (cols 0..63) and c=t+256 (cols 64..127)
  int lcol = t >> 2;
  int bsl  = t & 3;
  int bsw  = (bsl ^ ((lcol >> 1) & 3)) << 3;   // same for lcol and lcol+64
  int bc0  = (nt << 7) + lcol;
  int bc1  = bc0 + 64;
  const unsigned short* bS0 = u + (((size_t)((bc0>>5)*HH + h)) << 13) + ((bc0&31) << 8) + bsw;
  const unsigned short* bS1 = u + (((size_t)((bc1>>5)*HH + h)) << 13) + ((bc1&31) << 8) + bsw;

  // wave-uniform LDS destinations
  unsigned short* dA[2]  = { &sA2[0][wid<<9], &sA2[1][wid<<9] };
  unsigned short* dB0[2] = { &sB2[0][wid<<9], &sB2[1][wid<<9] };
  unsigned short* dB1[2] = { &sB2[0][2048 + (wid<<9)], &sB2[1][2048 + (wid<<9)] };

  // fragment read offsets (kt-independent)
  int aoff[2], boff[4];
  #pragma unroll
  for (int mi = 0; mi < 2; ++mi){
    int m = (wr<<5) + (mi<<4) + (lane&15);
    aoff[mi] = (m<<5) + (((lane>>4) ^ ((m>>1)&3))<<3);
  }
  #pragma unroll
  for (int ni = 0; ni < 4; ++ni){
    int c = (wc<<6) + (ni<<4) + (lane&15);
    boff[ni] = (c<<5) + (((lane>>4) ^ ((c>>1)&3))<<3);
  }

  f32x4 acc[2][4];
  #pragma unroll
  for (int mi = 0; mi < 2; ++mi)
    #pragma unroll
    for (int ni = 0; ni < 4; ++ni) acc[mi][ni] = (f32x4){0.f,0.f,0.f,0.f};

  // prologue: stage kt=0 into buffer 0
  gl16(aS, dA[0]);
  gl16(bS0, dB0[0]);
  gl16(bS1, dB1[0]);
  __syncthreads();

  #pragma unroll 2
  for (int kt = 0; kt < 8; ++kt){
    int cur = kt & 1;
    if (kt < 7){
      int k1o = (kt+1) << 5;
      gl16(aS  + k1o, dA[cur^1]);
      gl16(bS0 + k1o, dB0[cur^1]);
      gl16(bS1 + k1o, dB1[cur^1]);
    }
    const unsigned short* Ab = sA2[cur];
    const unsigned short* Bb = sB2[cur];
    bf16x8 af[2], bfv[4];
    #pragma unroll
    for (int mi = 0; mi < 2; ++mi) af[mi] = *(const bf16x8*)(Ab + aoff[mi]);
    #pragma unroll
    for (int ni = 0; ni < 4; ++ni) bfv[ni] = *(const bf16x8*)(Bb + boff[ni]);
    #pragma unroll
    for (int mi = 0; mi < 2; ++mi)
      #pragma unroll
      for (int ni = 0; ni < 4; ++ni)
        acc[mi][ni] = __builtin_amdgcn_mfma_f32_16x16x32_bf16(af[mi], bfv[ni], acc[mi][ni], 0,0,0);
    __syncthreads();
  }

  // epilogue: s_loc -> LDS sS[col][row] (ushort4 contiguous in row)
  #pragma unroll
  for (int ni = 0; ni < 4; ++ni){
    int lc = (wc<<6) + (ni<<4) + (lane&15);
    #pragma unroll
    for (int mi = 0; mi < 2; ++mi){
      int srow = (wr<<5) + (mi<<4) + ((lane>>4)<<2);
      ushort4 o;
      o.x = f2b(acc[mi][ni][0]); o.y = f2b(acc[mi][ni][1]);
      o.z = f2b(acc[mi][ni][2]); o.w = f2b(acc[mi][ni][3]);
      *(ushort4*)&sS[(lc<<6) + srow] = o;
    }
  }
  __syncthreads();

  // fused exclusive scan over chunks (was k2b): 128 threads = 4 b x 32 n
  if (t < 128){
    int bloc = t >> 5, n = t & 31;
    int b = (nt<<2) + bloc;
    int i0 = (h<<5) + n;
    float aTr = prm[32768 + i0], aTi = prm[40960 + i0];
    size_t base = (((size_t)b*HH + h)*NCH)*64 + (n<<1);
    float ir = 0.f, ii = 0.f;
    for (int c = 0; c < NCH; ++c){
      *(unsigned int*)(sbh + base + (size_t)(c<<6)) = ((unsigned int)f2b(ii)<<16) | f2b(ir);
      unsigned int rw = *(const unsigned int*)&sS[((bloc<<5) + c)*64 + (n<<1)];
      float lr = b2f(rw), li = b2f(rw>>16);
      float nr = fmaf(aTr, ir, fmaf(-aTi, ii, lr));
      float ni_ = fmaf(aTr, ii, fmaf(aTi, ir, li));
      ir = nr; ii = ni_;
    }
  }
}

// ---------------- K2c: y = gelu([K|E]*[u;s])  (fragment-A direct + LDS B) ----------------
__global__ __launch_bounds__(512, 4) void k2c_emit(unsigned short* __restrict__ uy,
                                                   const unsigned short* __restrict__ wke,
                                                   const unsigned short* __restrict__ sbh){
  __shared__ unsigned short sB[2][128*32];   // 2 x 8 KB
  __shared__ unsigned short sW[8][1152];     // per-wave 16 cols x 72 (64 m + 8 pad), 18 KB
  int bid = blockIdx.x;
  int lb = ((bid & 7) << 7) + (bid >> 3);    // 1024 = 8*128, XCD chunking
  int h = lb >> 2, nt = lb & 3;
  int t = threadIdx.x;
  int lane = t & 63, wid = t >> 6;
  int wr = wid >> 1, wc = wid & 1;

  const unsigned short* wkeh = wke + (size_t)h*81920;   // fragment-ordered

  // B staging: chunk c=t -> col t>>2 (0..127)
  int bcol = t >> 2;
  int bsl  = t & 3;
  int bsw  = (bsl ^ ((bcol >> 1) & 3)) << 3;
  int bcg  = (nt << 7) + bcol;
  int bb   = bcg >> 5, chk = bcg & 31;
  const unsigned short* bSU = uy  + (((size_t)(bb*HH + h)) << 13) + (chk << 8) + bsw;
  const unsigned short* bSS = sbh + (((size_t)bb*HH + h)*NCH + chk)*64 + bsw;

  unsigned short* dB0 = &sB[0][wid<<9];
  unsigned short* dB0b= &sB[1][wid<<9];

  // A fragment row indices (kt-independent)
  int am[4];
  #pragma unroll
  for (int mi = 0; mi < 4; ++mi) am[mi] = (wr<<6) + (mi<<4) + (lane&15);
  // B fragment read offsets
  int boff[4];
  #pragma unroll
  for (int ni = 0; ni < 4; ++ni){
    int c = (wc<<6) + (ni<<4) + (lane&15);
    boff[ni] = (c<<5) + (((lane>>4) ^ ((c>>1)&3))<<3);
  }

  f32x4 acc[4][4];
  #pragma unroll
  for (int mi = 0; mi < 4; ++mi)
    #pragma unroll
    for (int ni = 0; ni < 4; ++ni) acc[mi][ni] = (f32x4){0.f,0.f,0.f,0.f};

  // prologue: stage B step 0 into buffer 0
  gl16(bSU, dB0);
  __syncthreads();

  #pragma unroll 2
  for (int kt = 0; kt < 10; ++kt){
    int cur = kt & 1;
    if (kt < 9){                         // prefetch B step kt+1 into other buffer
      int k1o = (kt+1) << 5;
      const unsigned short* bs = (kt+1 < 8) ? (bSU + k1o) : (bSS + ((kt+1-8) << 5));
      gl16(bs, cur ? dB0 : dB0b);
    }
    int q = (kt<<2) + (lane>>4);
    const unsigned short* Ab = wkeh + ((size_t)q<<11);
    const unsigned short* Bb = sB[cur];
    bf16x8 af[4], bfv[4];
    #pragma unroll
    for (int mi = 0; mi < 4; ++mi) af[mi] = *(const bf16x8*)(Ab + (am[mi]<<3));
    #pragma unroll
    for (int ni = 0; ni < 4; ++ni) bfv[ni] = *(const bf16x8*)(Bb + boff[ni]);
    #pragma unroll
    for (int mi = 0; mi < 4; ++mi)
      #pragma unroll
      for (int ni = 0; ni < 4; ++ni)
        acc[mi][ni] = __builtin_amdgcn_mfma_f32_16x16x32_bf16(af[mi], bfv[ni], acc[mi][ni], 0,0,0);
    __syncthreads();                     // drains prefetch + protects buffer reuse
  }

  // epilogue: per-wave LDS transpose (col-major 72-stride), no barriers.
  unsigned short* wbase = sW[wid];
  int col16 = lane & 15;                 // staging column within 16-col group
  int rcol  = lane >> 2;                 // copy-out column (0..15)
  int rseg  = lane & 3;                  // copy-out 16-m segment
  #pragma unroll
  for (int ni = 0; ni < 4; ++ni){
    #pragma unroll
    for (int mi = 0; mi < 4; ++mi){
      int mloc = (mi<<4) + ((lane>>4)<<2);
      ushort4 o;
      #pragma unroll
      for (int rr = 0; rr < 4; ++rr)
        ((unsigned short*)&o)[rr] = f2b(gelu_t(acc[mi][ni][rr]));
      *(ushort4*)&wbase[col16*72 + mloc] = o;
    }
    int bcO = (nt<<7) + (wc<<6) + (ni<<4) + rcol;
    unsigned short* op = uy + (((size_t)((bcO>>5)*HH + h))<<13) + ((bcO&31)<<8)
                       + (wr<<6) + (rseg<<4);
    uint4 va = *(const uint4*)&wbase[rcol*72 + (rseg<<4)];
    uint4 vb = *(const uint4*)&wbase[rcol*72 + (rseg<<4) + 8];
    *(uint4*)op       = va;
    *(uint4*)(op + 8) = vb;
  }
}

// ---------------- K3: GLU GEMM via MFMA + fused max-pool ----------------
// T10: y-tile staged into LDS in natural l-contiguous order via global_load_lds
// (async, replaces 32 scalar ds_write_u16 + addr VALU per thread/kt), arranged
// as 4x16 subtiles: off(h,l) = ((h>>2)*8+(l>>4))*64 + (h&3)*16 + (l&15).
// A-fragments read with ds_read_b64_tr_b16 (HW transpose): per-lane addr =
// subtile_base + (lane&15)*8B; two reads per fragment (h-halves).
__global__ __launch_bounds__(512) void k3_glu(const unsigned short* __restrict__ y,
                                              const unsigned short* __restrict__ wot,
                                              const float* __restrict__ bo,
                                              float* __restrict__ part){
  __shared__ unsigned short sA[128*64];       // subtiled (16 KB), shared by both groups
  __shared__ unsigned short sB[2][128*64];    // per-group (2 x 16 KB)
  __shared__ float smax[2][256];
  int t = threadIdx.x;
  int lane = t & 63, wid = t >> 6;
  int wg = wid >> 2;          // wave-group 0/1
  int wl = wid & 3;           // wave within group
  int bid = blockIdx.x;
  int lb = ((bid & 7) << 8) + (bid >> 3);     // 2048 = 8*256, XCD chunking
  int js2 = lb & 1, mb = (lb >> 1) & 63, b = lb >> 7;
  int js = (js2 << 1) + wg;   // this group's js (0..3)
  f32x4 acc[2][8];
  #pragma unroll
  for (int i = 0; i < 2; ++i)
    #pragma unroll
    for (int j = 0; j < 8; ++j)
      acc[i][j] = (f32x4){0.f,0.f,0.f,0.f};

  // A staging: chunk c -> (h,l): h = ((c>>6)<<2) + ((c&7)>>1), l = ((c>>3)&7)*16 + (c&1)*8
  int c0 = t, c1 = t + 512;
  int h0 = ((c0>>6)<<2) + ((c0&7)>>1);
  int l0 = (((c0>>3)&7)<<4) + ((c0&1)<<3);
  int h1 = ((c1>>6)<<2) + ((c1&7)>>1);
  int l1 = (((c1>>3)&7)<<4) + ((c1&1)<<3);
  unsigned short* dA0 = &sA[wid<<9];          // wave-uniform dests (lane adds 16B)
  unsigned short* dA1 = &sA[4096 + (wid<<9)];

  // tr-read per-thread base (bytes): g*2048 + wl*256 + (lane&15)*8
  unsigned sAb = (unsigned)(size_t)(lds_u16_t*)&sA[0];
  unsigned trb = sAb + ((unsigned)(lane>>4)<<11) + ((unsigned)wl<<8) + ((unsigned)(lane&15)<<3);

  for (int kt = 0; kt < 4; ++kt){
    __syncthreads();
    {
      const unsigned short* s0 = y + (((size_t)(b*HH + (kt<<6) + h0))<<13) + (mb<<7) + l0;
      const unsigned short* s1 = y + (((size_t)(b*HH + (kt<<6) + h1))<<13) + (mb<<7) + l1;
      gl16(s0, dA0);
      gl16(s1, dA1);
    }
    {
      // B: each group stages its own js half (unchanged)
      int tt = t & 255;
      #pragma unroll
      for (int p = 0; p < 4; ++p){
        int idx = (p<<8) + tt;
        int row = idx >> 3, sl = idx & 7;
        int ng = (row < 64) ? ((js<<6) + row) : (256 + (js<<6) + row - 64);
        const float4 v = *(const float4*)(wot + (ng<<8) + (kt<<6) + (sl<<3));
        *(float4*)&sB[wg][(row<<6) + ((sl ^ (row&7))<<3)] = v;
      }
    }
    __syncthreads();
    #pragma unroll
    for (int kk = 0; kk < 2; ++kk){
      // A fragments via HW transpose read: addr(kk,mi,p) = trb + kk*8192 + p*1024 + mi*128
      s16x4 L0, H0, L1, H1;
      unsigned a00 = trb + ((unsigned)kk<<13);
      unsigned a01 = a00 + 1024;
      unsigned a10 = a00 + 128;
      unsigned a11 = a00 + 1152;
      asm volatile(
        "ds_read_b64_tr_b16 %0, %4\n\t"
        "ds_read_b64_tr_b16 %1, %5\n\t"
        "ds_read_b64_tr_b16 %2, %6\n\t"
        "ds_read_b64_tr_b16 %3, %7\n\t"
        "s_waitcnt lgkmcnt(0)"
        : "=&v"(L0), "=&v"(H0), "=&v"(L1), "=&v"(H1)
        : "v"(a00), "v"(a01), "v"(a10), "v"(a11));
      __builtin_amdgcn_sched_barrier(0);
      bf16x8 af[2];
      #pragma unroll
      for (int e = 0; e < 4; ++e){
        af[0][e] = L0[e]; af[0][4+e] = H0[e];
        af[1][e] = L1[e]; af[1][4+e] = H1[e];
      }
      bf16x8 bfr[8];
      #pragma unroll
      for (int ni = 0; ni < 8; ++ni){
        int r = (ni<<4) + (lane&15);
        int sl = (kk<<2) + (lane>>4);
        bfr[ni] = *(const bf16x8*)&sB[wg][(r<<6) + ((sl ^ (r&7))<<3)];
      }
      #pragma unroll
      for (int ni = 0; ni < 8; ++ni)
        #pragma unroll
        for (int mi = 0; mi < 2; ++mi)
          acc[mi][ni] = __builtin_amdgcn_mfma_f32_16x16x32_bf16(af[mi], bfr[ni], acc[mi][ni], 0, 0, 0);
    }
  }

  float bo1[4], bo2[4];
  #pragma unroll
  for (int ni = 0; ni < 4; ++ni){
    int col = (js<<6) + (ni<<4) + (lane&15);
    bo1[ni] = bo[col]; bo2[ni] = bo[256 + col];
  }
  #pragma unroll
  for (int ni = 0; ni < 4; ++ni){
    float m = -3.4e38f;
    #pragma unroll
    for (int mi = 0; mi < 2; ++mi)
      #pragma unroll
      for (int r = 0; r < 4; ++r){
        float v1 = acc[mi][ni][r] + bo1[ni];
        float v2 = acc[mi][ni+4][r] + bo2[ni];
        float g = v1 * (1.0f/(1.0f + __expf(-v2)));
        m = fmaxf(m, g);
      }
    m = fmaxf(m, __shfl_xor(m, 16));
    m = fmaxf(m, __shfl_xor(m, 32));
    if (lane < 16) smax[wg][(wl<<6) + (ni<<4) + lane] = m;
  }
  __syncthreads();
  if (t < 128){
    int wg2 = t >> 6, tt = t & 63;
    int jso = (js2 << 1) + wg2;
    float m = fmaxf(fmaxf(smax[wg2][tt], smax[wg2][64+tt]),
                    fmaxf(smax[wg2][128+tt], smax[wg2][192+tt]));
    part[(((size_t)b<<6) + mb)*256 + (jso<<6) + tt] = m;
  }
}

// ---------------- K3.5 / K4a / K4b ----------------
__global__ void k35_pool(const float* __restrict__ part, float* __restrict__ pool){
  int b = blockIdx.x, j = threadIdx.x;
  float m = -3.4e38f;
  for (int mb = 0; mb < 64; ++mb)
    m = fmaxf(m, part[(((size_t)b<<6) + mb)*256 + j]);
  pool[(b<<8) + j] = m;
}
__global__ void k4a_fc2(const float* __restrict__ pool, const float* __restrict__ W2,
                        const float* __restrict__ b2, float* __restrict__ f){
  int id = blockIdx.x*256 + threadIdx.x;
  int b = id >> 9, ko = id & 511;
  float s = b2[ko];
  #pragma unroll 8
  for (int hh = 0; hh < 256; ++hh)
    s = fmaf(pool[(b<<8) + hh], W2[hh*512 + ko], s);
  f[id] = s > 0.0f ? s : 0.01f*s;
}
__global__ void k4b_head(const float* __restrict__ f, const float* __restrict__ W3,
                         const float* __restrict__ b3, float* __restrict__ out){
  __shared__ float lg[160];
  int t = threadIdx.x;
  if (t < 160){
    int b = t/10, c = t - 10*b;
    float s = b3[c];
    #pragma unroll 8
    for (int ko = 0; ko < 512; ++ko)
      s = fmaf(f[(b<<9) + ko], W3[ko*10 + c], s);
    lg[t] = s;
    out[t] = s;
  }
  __syncthreads();
  if (t < 10){
    int bi = 0; float bvv = lg[t];
    for (int b2i = 1; b2i < 16; ++b2i){
      float vv = lg[b2i*10 + t];
      if (vv > bvv){ bvv = vv; bi = b2i; }
    }
    out[160 + t] = (float)bi;
  }
}

extern "C" void kernel_launch(void* const* d_in, const int* in_sizes, int n_in,
                              void* d_out, int out_size, void* d_ws, size_t ws_size,
                              hipStream_t stream) {
  const float* x      = (const float*)d_in[0];
  const float* W1     = (const float*)d_in[1];
  const float* b1     = (const float*)d_in[2];
  const float* lng    = (const float*)d_in[3];
  const float* lnb    = (const float*)d_in[4];
  const float* log_dt = (const float*)d_in[5];
  const float* logA   = (const float*)d_in[6];
  const float* Aim    = (const float*)d_in[7];
  const float* Cre    = (const float*)d_in[8];
  const float* Cim    = (const float*)d_in[9];
  const float* Dp     = (const float*)d_in[10];
  const float* Wo     = (const float*)d_in[11];
  const float* bo     = (const float*)d_in[12];
  const float* W2     = (const float*)d_in[13];
  const float* b2     = (const float*)d_in[14];
  const float* W3     = (const float*)d_in[15];
  const float* b3     = (const float*)d_in[16];
  char* wsb = (char*)d_ws;
  unsigned short* u   = (unsigned short*)(wsb + U_OFF);
  float* prm          = (float*)(wsb + PRM_OFF);
  unsigned short* wke = (unsigned short*)(wsb + WKE_OFF);
  unsigned short* fb  = (unsigned short*)(wsb + F_OFF);
  unsigned short* sbh = (unsigned short*)(wsb + SBH_OFF);
  unsigned short* w1t = (unsigned short*)(wsb + W1T_OFF);
  unsigned short* wot = (unsigned short*)(wsb + WOT_OFF);
  float* part         = (float*)(wsb + PART_OFF);
  float* pool         = (float*)(wsb + POOL_OFF);
  float* fbuf         = (float*)(wsb + FC_OFF);
  float* out          = (float*)d_out;

  kp_all   <<<dim3(10912),dim3(256), 0, stream>>>(log_dt, logA, Aim, Cre, Cim, prm,
                                                  Wo, wot, W1, w1t, wke, fb);
  kp_khw   <<<dim3(256),  dim3(256), 0, stream>>>(prm, Dp, wke);
  k1_fc1_ln<<<dim3(2048), dim3(512), 0, stream>>>(x, w1t, b1, lng, lnb, u);
  k2a_states<<<dim3(1024),dim3(256), 0, stream>>>(u, fb, prm, sbh);
  k2c_emit <<<dim3(1024), dim3(512), 0, stream>>>(u, wke, sbh);
  k3_glu   <<<dim3(2048), dim3(512), 0, stream>>>(u, wot, bo, part);
  k35_pool <<<dim3(16),   dim3(256), 0, stream>>>(part, pool);
  k4a_fc2  <<<dim3(32),   dim3(256), 0, stream>>>(pool, W2, b2, fbuf);
  k4b_head <<<dim3(1),    dim3(256), 0, stream>>>(fbuf, W3, b3, out);
}

// Round 23
// 242.787 us; speedup vs baseline: 1.0821x; 1.0821x over previous
//
#include <hip/hip_runtime.h>
#include <math.h>

typedef float f32x4 __attribute__((ext_vector_type(4)));
typedef short bf16x8 __attribute__((ext_vector_type(8)));

#define BB 16
#define LL 8192
#define DIN 128
#define HH 256
#define NCH 32
#define TCH 256

// ---------------- workspace layout (byte offsets) ----------------
#define U_OFF    0ull            // u/y bf16 (B,H,L) 67108864
#define PRM_OFF  67108864ull     // prm fp32 8 planes x 8192
#define KK_OFF   67371008ull     // [unused]
#define WKE_OFF  67633152ull     // WKE bf16 FRAGMENT-ORDER (256h x 40q x 256m x 8c) 41943040
#define F_OFF    109576192ull    // F bf16 (256h,64,256) 8388608
#define SB_OFF   117964800ull    // [unused]
#define SBH_OFF  134742016ull    // s_in  bf16 (B,H,32,64) 16777216
#define W1T_OFF  151519232ull    // W1 fragment-ordered bf16 (16,256,8)
#define WOT_OFF  151584768ull    // Wo^T bf16 (512,256)
#define PART_OFF 151846912ull    // part fp32 (B,64,256)
#define POOL_OFF 152895488ull
#define FC_OFF   152911872ull

static __device__ __forceinline__ unsigned short f2b(float f){
  unsigned int u = __float_as_uint(f);
  return (unsigned short)((u + 0x7fffu + ((u>>16)&1u)) >> 16);
}
static __device__ __forceinline__ float b2f(unsigned int h){
  return __uint_as_float((h & 0xffffu)<<16);
}

// tanh-approx GELU: v * sigmoid(2*sqrt(2/pi)*(v + 0.044715 v^3))
static __device__ __forceinline__ float gelu_t(float v){
  float vv = v*v;
  float p  = fmaf(0.044715f, vv, 1.0f);
  float z  = v*p*(-1.5957691216057308f);
  float e  = __expf(z);
  return v*__builtin_amdgcn_rcpf(1.0f + e);
}

// async global->LDS, 16B per lane; LDS dest must be wave-uniform base (HW adds lane*16)
typedef __attribute__((address_space(3))) unsigned int lds_u32_t;
typedef const __attribute__((address_space(1))) unsigned int glb_u32_t;
static __device__ __forceinline__ void gl16(const void* g, void* l){
  __builtin_amdgcn_global_load_lds((glb_u32_t*)g, (lds_u32_t*)l, 16, 0, 0);
}

// ---------------- KP_ALL: fused independent prologue ----------------
// ranges: [0,32) k0-prm | [32,544) kw_wot | [544,672) kw_w1t |
//         [672,2720) E (parallel, fragment layout) | [2720,10912) F (parallel)
__global__ __launch_bounds__(256) void kp_all(
    const float* __restrict__ log_dt, const float* __restrict__ log_A_real,
    const float* __restrict__ A_imag, const float* __restrict__ C_re,
    const float* __restrict__ C_im, float* __restrict__ prm,
    const float* __restrict__ Wo, unsigned short* __restrict__ wot,
    const float* __restrict__ W1, unsigned short* __restrict__ w1t,
    unsigned short* __restrict__ wke, unsigned short* __restrict__ fb){
  int bid = blockIdx.x;
  int t = threadIdx.x;
  if (bid < 32){
    // ---- k0: S4D discretized parameters (prm planes; scan needs aT) ----
    int id = bid*256 + t;
    int h = id >> 5;
    float dt = expf(log_dt[h]);
    float Ar = -expf(log_A_real[id]);
    float Ai = A_imag[id];
    float dr = Ar*dt, di = Ai*dt;
    float ear = expf(dr);
    float are = ear*cosf(di), aim = ear*sinf(di);
    float er = are - 1.0f, ei = aim;
    float den = 1.0f/(Ar*Ar + Ai*Ai);
    float Br = (er*Ar + ei*Ai)*den;
    float Bi = (ei*Ar - er*Ai)*den;
    float c_r = C_re[id], c_i = C_im[id];
    float cre = 2.0f*(c_r*Br - c_i*Bi);
    float cim = 2.0f*(c_r*Bi + c_i*Br);
    double phi = (double)di*(double)TCH;
    float eT = expf(dr*(float)TCH);
    float aTre = eT*(float)cos(phi);
    float aTim = eT*(float)sin(phi);
    prm[id]         = are;  prm[8192  + id] = aim;
    prm[16384 + id] = cre;  prm[24576 + id] = cim;
    prm[32768 + id] = aTre; prm[40960 + id] = aTim;
    prm[49152 + id] = dr;   prm[57344 + id] = di;
  } else if (bid < 544){
    // ---- kw_wot ----
    int id = (bid-32)*256 + t;        // 131072
    int k = id >> 9, n = id & 511;
    wot[n*256 + k] = f2b(Wo[id]);
  } else if (bid < 672){
    // ---- kw_w1t (fragment order) ----
    int id = (bid-544)*256 + t;       // 32768
    int k = id >> 8, n = id & 255;
    w1t[((k>>3)<<11) + (n<<3) + (k&7)] = f2b(W1[k*256 + n]);
  } else if (bid < 2720){
    // ---- E into WKE fragment layout, computed per-element (a^{m+1}) ----
    int bid2 = bid - 672;             // 2048 = (h, ngroup)
    int h = bid2 >> 3, ng = bid2 & 7;
    int nn = t & 3;                   // n within group
    int n  = (ng<<2) + nn;
    int hn = (h<<5) + n;
    float dt = expf(log_dt[h]);
    float Ar = -expf(log_A_real[hn]);
    float Ai = A_imag[hn];
    float dr = Ar*dt, di = Ai*dt;
    float ear = expf(dr);
    float are = ear*cosf(di), aim = ear*sinf(di);
    float er = are - 1.0f, ei = aim;
    float den = 1.0f/(Ar*Ar + Ai*Ai);
    float Br = (er*Ar + ei*Ai)*den;
    float Bi = (ei*Ar - er*Ai)*den;
    float c_r = C_re[hn], c_i = C_im[hn];
    float cre = 2.0f*(c_r*Br - c_i*Bi);
    float cim = 2.0f*(c_r*Bi + c_i*Br);
    int q = 32 + ng, c = nn << 1;
    unsigned short* W = wke + (size_t)h*81920 + ((size_t)q<<11) + c;
    int mb = t >> 2;
    #pragma unroll
    for (int i = 0; i < 4; ++i){
      int m = mb + (i<<6);
      float fm = (float)(m+1);
      float E  = expf(dr*fm);
      float ph = di*fm;
      float car = E*cosf(ph), sar = E*sinf(ph);
      float zr = cre*car - cim*sar;
      float zi = cre*sar + cim*car;
      *(unsigned int*)(W + (m<<3)) = ((unsigned int)f2b(-zi)<<16) | f2b(zr);
    }
  } else {
    // ---- F per-element: Fh[j] = a^{255-j} ----
    int bid3 = bid - 2720;            // 8192 = (h,n)
    int h = bid3 >> 5, n = bid3 & 31;
    int hn = (h<<5) + n;
    float dt = expf(log_dt[h]);
    float Ar = -expf(log_A_real[hn]);
    float Ai = A_imag[hn];
    float dr = Ar*dt, di = Ai*dt;
    int j = t;
    float fp = (float)(255 - j);
    float E  = expf(dr*fp);
    float ph = di*fp;
    unsigned short* Fh = fb + ((size_t)h<<14) + (n<<9);
    Fh[j]       = f2b(E*cosf(ph));
    Fh[256 + j] = f2b(E*sinf(ph));
  }
}

// ---------------- KP_KHW: fused kernel-taps + Toeplitz WKE (per head) ----------------
__global__ __launch_bounds__(256) void kp_khw(const float* __restrict__ prm,
                                              const float* __restrict__ Dp,
                                              unsigned short* __restrict__ wke){
  __shared__ float kh[256];
  int h = blockIdx.x;
  int d = threadIdx.x;
  {
    float fd = (float)d;
    float s = 0.f;
    #pragma unroll 8
    for (int n = 0; n < 32; ++n){
      int i0 = (h<<5) + n;
      float dr = prm[49152 + i0], di = prm[57344 + i0];
      float cr = prm[16384 + i0], ci = prm[24576 + i0];
      float e = expf(dr*fd);
      float ph = di*fd;
      s += e*(cr*cosf(ph) - ci*sinf(ph));
    }
    kh[d] = s;
  }
  __syncthreads();
  int m = threadIdx.x;
  float dp = Dp[h];
  unsigned short* W = wke + (size_t)h*81920;
  for (int j4 = 0; j4 < 256; j4 += 4){
    ushort4 o;
    float v0 = (j4+0 <= m) ? kh[m-j4-0] : 0.f; if (j4+0 == m) v0 += dp;
    float v1 = (j4+1 <= m) ? kh[m-j4-1] : 0.f; if (j4+1 == m) v1 += dp;
    float v2 = (j4+2 <= m) ? kh[m-j4-2] : 0.f; if (j4+2 == m) v2 += dp;
    float v3 = (j4+3 <= m) ? kh[m-j4-3] : 0.f; if (j4+3 == m) v3 += dp;
    o.x = f2b(v0); o.y = f2b(v1); o.z = f2b(v2); o.w = f2b(v3);
    *(ushort4*)(W + (((j4>>3)<<11)) + (m<<3) + (j4&7)) = o;
  }
}

// ---------------- K1: fc1 + ReLU + LayerNorm (MFMA) -> u bf16 (B,H,L) ----------------
__global__ __launch_bounds__(512, 4) void k1_fc1_ln(const float* __restrict__ x,
    const unsigned short* __restrict__ w1t, const float* __restrict__ b1,
    const float* __restrict__ lng, const float* __restrict__ lnb,
    unsigned short* __restrict__ u){
  __shared__ unsigned short sX[64*128];
  __shared__ float sRed[4][64][2];
  int t = threadIdx.x;
  int lane = t & 63, wid = t >> 6;
  int wr = wid >> 2, wc = wid & 3;
  int g0 = blockIdx.x << 6;
  int b = g0 >> 13, l0 = g0 & 8191;
  {
    int r = t >> 3, kq = (t & 7) << 4;
    const float* xr = x + (size_t)(g0 + r)*DIN + kq;
    #pragma unroll
    for (int i = 0; i < 4; ++i){
      float4 v = *(const float4*)(xr + i*4);
      ushort4 o; o.x=f2b(v.x); o.y=f2b(v.y); o.z=f2b(v.z); o.w=f2b(v.w);
      int k0 = kq + i*4;
      int q = k0 >> 3;
      *(ushort4*)&sX[(r<<7) + ((q ^ (r&7))<<3) + (k0&7)] = o;
    }
  }
  __syncthreads();
  f32x4 acc[2][4];
  #pragma unroll
  for (int mi = 0; mi < 2; ++mi)
    #pragma unroll
    for (int ni = 0; ni < 4; ++ni) acc[mi][ni] = (f32x4){0.f,0.f,0.f,0.f};
  #pragma unroll
  for (int kt = 0; kt < 4; ++kt){
    bf16x8 af[2];
    #pragma unroll
    for (int mi = 0; mi < 2; ++mi){
      int m = (wr<<5) + (mi<<4) + (lane&15);
      int q = (kt<<2) + (lane>>4);
      af[mi] = *(const bf16x8*)&sX[(m<<7) + ((q ^ (m&7))<<3)];
    }
    #pragma unroll
    for (int ni = 0; ni < 4; ++ni){
      int hcol = (wc<<6) + (ni<<4) + (lane&15);
      bf16x8 bf = *(const bf16x8*)(w1t + (((kt<<2) + (lane>>4))<<11) + (hcol<<3));
      acc[0][ni] = __builtin_amdgcn_mfma_f32_16x16x32_bf16(af[0], bf, acc[0][ni], 0,0,0);
      acc[1][ni] = __builtin_amdgcn_mfma_f32_16x16x32_bf16(af[1], bf, acc[1][ni], 0,0,0);
    }
  }
  float bv[4];
  #pragma unroll
  for (int ni = 0; ni < 4; ++ni) bv[ni] = b1[(wc<<6) + (ni<<4) + (lane&15)];
  float s1[2][4] = {{0,0,0,0},{0,0,0,0}}, s2[2][4] = {{0,0,0,0},{0,0,0,0}};
  #pragma unroll
  for (int mi = 0; mi < 2; ++mi)
    #pragma unroll
    for (int ni = 0; ni < 4; ++ni)
      #pragma unroll
      for (int rr = 0; rr < 4; ++rr){
        float v = acc[mi][ni][rr] + bv[ni];
        v = v > 0.f ? v : 0.f;
        acc[mi][ni][rr] = v;
        s1[mi][rr] += v; s2[mi][rr] = fmaf(v, v, s2[mi][rr]);
      }
  #pragma unroll
  for (int off = 1; off < 16; off <<= 1)
    #pragma unroll
    for (int mi = 0; mi < 2; ++mi)
      #pragma unroll
      for (int rr = 0; rr < 4; ++rr){
        s1[mi][rr] += __shfl_xor(s1[mi][rr], off);
        s2[mi][rr] += __shfl_xor(s2[mi][rr], off);
      }
  if ((lane & 15) == 0){
    #pragma unroll
    for (int mi = 0; mi < 2; ++mi)
      #pragma unroll
      for (int rr = 0; rr < 4; ++rr){
        int row = (wr<<5) + (mi<<4) + ((lane>>4)<<2) + rr;
        sRed[wc][row][0] = s1[mi][rr];
        sRed[wc][row][1] = s2[mi][rr];
      }
  }
  __syncthreads();
  float mu[2][4], rs[2][4];
  #pragma unroll
  for (int mi = 0; mi < 2; ++mi)
    #pragma unroll
    for (int rr = 0; rr < 4; ++rr){
      int row = (wr<<5) + (mi<<4) + ((lane>>4)<<2) + rr;
      float t1 = sRed[0][row][0] + sRed[1][row][0] + sRed[2][row][0] + sRed[3][row][0];
      float t2 = sRed[0][row][1] + sRed[1][row][1] + sRed[2][row][1] + sRed[3][row][1];
      float m_ = t1*(1.f/256.f);
      mu[mi][rr] = m_;
      rs[mi][rr] = rsqrtf(t2*(1.f/256.f) - m_*m_ + 1e-5f);
    }
  #pragma unroll
  for (int ni = 0; ni < 4; ++ni){
    int hcol = (wc<<6) + (ni<<4) + (lane&15);
    float g = lng[hcol], bb = lnb[hcol];
    #pragma unroll
    for (int mi = 0; mi < 2; ++mi){
      ushort4 o;
      o.x = f2b((acc[mi][ni][0]-mu[mi][0])*rs[mi][0]*g + bb);
      o.y = f2b((acc[mi][ni][1]-mu[mi][1])*rs[mi][1]*g + bb);
      o.z = f2b((acc[mi][ni][2]-mu[mi][2])*rs[mi][2]*g + bb);
      o.w = f2b((acc[mi][ni][3]-mu[mi][3])*rs[mi][3]*g + bb);
      *(ushort4*)(u + (((size_t)(b*HH + hcol))<<13) + l0 + (wr<<5) + (mi<<4) + ((lane>>4)<<2)) = o;
    }
  }
}

// ---------------- K2a: s_loc = F * u  + FUSED chunk-prefix scan -> sbh ----------------
__global__ __launch_bounds__(256, 4) void k2a_states(const unsigned short* __restrict__ u,
                                                     const unsigned short* __restrict__ fb,
                                                     const float* __restrict__ prm,
                                                     unsigned short* __restrict__ sbh){
  __shared__ unsigned short sA2[2][64*32];    // 2 x 4 KB
  __shared__ unsigned short sB2[2][128*32];   // 2 x 8 KB
  __shared__ unsigned short sS[128*64];       // s_loc [col][row] 16 KB
  int bid = blockIdx.x;
  int lb = ((bid & 7) << 7) + (bid >> 3);   // 1024 = 8*128, XCD chunking
  int h = lb >> 2, nt = lb & 3;
  int t = threadIdx.x;
  int lane = t & 63, wid = t >> 6;
  int wr = wid >> 1, wc = wid & 1;

  // A staging: chunk c=t -> row t>>2 (0..63), slot t&3; source pre-swizzled
  int ar0 = t >> 2;
  int asl = t & 3;
  int asw = (asl ^ ((ar0 >> 1) & 3)) << 3;
  const unsigned short* aS = fb + ((size_t)h<<14) + ar0*256 + asw;

  // B staging: chunks c=t (cols 0..63) and c=t+256 (cols 64..127)
  int lcol = t >> 2;
  int bsl  = t & 3;
  int bsw  = (bsl ^ ((lcol >> 1) & 3)) << 3;   // same for lcol and lcol+64
  int bc0  = (nt << 7) + lcol;
  int bc1  = bc0 + 64;
  const unsigned short* bS0 = u + (((size_t)((bc0>>5)*HH + h)) << 13) + ((bc0&31) << 8) + bsw;
  const unsigned short* bS1 = u + (((size_t)((bc1>>5)*HH + h)) << 13) + ((bc1&31) << 8) + bsw;

  // wave-uniform LDS destinations
  unsigned short* dA[2]  = { &sA2[0][wid<<9], &sA2[1][wid<<9] };
  unsigned short* dB0[2] = { &sB2[0][wid<<9], &sB2[1][wid<<9] };
  unsigned short* dB1[2] = { &sB2[0][2048 + (wid<<9)], &sB2[1][2048 + (wid<<9)] };

  // fragment read offsets (kt-independent)
  int aoff[2], boff[4];
  #pragma unroll
  for (int mi = 0; mi < 2; ++mi){
    int m = (wr<<5) + (mi<<4) + (lane&15);
    aoff[mi] = (m<<5) + (((lane>>4) ^ ((m>>1)&3))<<3);
  }
  #pragma unroll
  for (int ni = 0; ni < 4; ++ni){
    int c = (wc<<6) + (ni<<4) + (lane&15);
    boff[ni] = (c<<5) + (((lane>>4) ^ ((c>>1)&3))<<3);
  }

  f32x4 acc[2][4];
  #pragma unroll
  for (int mi = 0; mi < 2; ++mi)
    #pragma unroll
    for (int ni = 0; ni < 4; ++ni) acc[mi][ni] = (f32x4){0.f,0.f,0.f,0.f};

  // prologue: stage kt=0 into buffer 0
  gl16(aS, dA[0]);
  gl16(bS0, dB0[0]);
  gl16(bS1, dB1[0]);
  __syncthreads();

  #pragma unroll 2
  for (int kt = 0; kt < 8; ++kt){
    int cur = kt & 1;
    if (kt < 7){
      int k1o = (kt+1) << 5;
      gl16(aS  + k1o, dA[cur^1]);
      gl16(bS0 + k1o, dB0[cur^1]);
      gl16(bS1 + k1o, dB1[cur^1]);
    }
    const unsigned short* Ab = sA2[cur];
    const unsigned short* Bb = sB2[cur];
    bf16x8 af[2], bfv[4];
    #pragma unroll
    for (int mi = 0; mi < 2; ++mi) af[mi] = *(const bf16x8*)(Ab + aoff[mi]);
    #pragma unroll
    for (int ni = 0; ni < 4; ++ni) bfv[ni] = *(const bf16x8*)(Bb + boff[ni]);
    #pragma unroll
    for (int mi = 0; mi < 2; ++mi)
      #pragma unroll
      for (int ni = 0; ni < 4; ++ni)
        acc[mi][ni] = __builtin_amdgcn_mfma_f32_16x16x32_bf16(af[mi], bfv[ni], acc[mi][ni], 0,0,0);
    __syncthreads();
  }

  // epilogue: s_loc -> LDS sS[col][row] (ushort4 contiguous in row)
  #pragma unroll
  for (int ni = 0; ni < 4; ++ni){
    int lc = (wc<<6) + (ni<<4) + (lane&15);
    #pragma unroll
    for (int mi = 0; mi < 2; ++mi){
      int srow = (wr<<5) + (mi<<4) + ((lane>>4)<<2);
      ushort4 o;
      o.x = f2b(acc[mi][ni][0]); o.y = f2b(acc[mi][ni][1]);
      o.z = f2b(acc[mi][ni][2]); o.w = f2b(acc[mi][ni][3]);
      *(ushort4*)&sS[(lc<<6) + srow] = o;
    }
  }
  __syncthreads();

  // fused exclusive scan over chunks (was k2b): 128 threads = 4 b x 32 n
  if (t < 128){
    int bloc = t >> 5, n = t & 31;
    int b = (nt<<2) + bloc;
    int i0 = (h<<5) + n;
    float aTr = prm[32768 + i0], aTi = prm[40960 + i0];
    size_t base = (((size_t)b*HH + h)*NCH)*64 + (n<<1);
    float ir = 0.f, ii = 0.f;
    for (int c = 0; c < NCH; ++c){
      *(unsigned int*)(sbh + base + (size_t)(c<<6)) = ((unsigned int)f2b(ii)<<16) | f2b(ir);
      unsigned int rw = *(const unsigned int*)&sS[((bloc<<5) + c)*64 + (n<<1)];
      float lr = b2f(rw), li = b2f(rw>>16);
      float nr = fmaf(aTr, ir, fmaf(-aTi, ii, lr));
      float ni_ = fmaf(aTr, ii, fmaf(aTi, ir, li));
      ir = nr; ii = ni_;
    }
  }
}

// ---------------- K2c: y = gelu([K|E]*[u;s])  (fragment-A direct + LDS B) ----------------
__global__ __launch_bounds__(512, 4) void k2c_emit(unsigned short* __restrict__ uy,
                                                   const unsigned short* __restrict__ wke,
                                                   const unsigned short* __restrict__ sbh){
  __shared__ unsigned short sB[2][128*32];   // 2 x 8 KB
  __shared__ unsigned short sW[8][1152];     // per-wave 16 cols x 72 (64 m + 8 pad), 18 KB
  int bid = blockIdx.x;
  int lb = ((bid & 7) << 7) + (bid >> 3);    // 1024 = 8*128, XCD chunking
  int h = lb >> 2, nt = lb & 3;
  int t = threadIdx.x;
  int lane = t & 63, wid = t >> 6;
  int wr = wid >> 1, wc = wid & 1;

  const unsigned short* wkeh = wke + (size_t)h*81920;   // fragment-ordered

  // B staging: chunk c=t -> col t>>2 (0..127)
  int bcol = t >> 2;
  int bsl  = t & 3;
  int bsw  = (bsl ^ ((bcol >> 1) & 3)) << 3;
  int bcg  = (nt << 7) + bcol;
  int bb   = bcg >> 5, chk = bcg & 31;
  const unsigned short* bSU = uy  + (((size_t)(bb*HH + h)) << 13) + (chk << 8) + bsw;
  const unsigned short* bSS = sbh + (((size_t)bb*HH + h)*NCH + chk)*64 + bsw;

  unsigned short* dB0 = &sB[0][wid<<9];
  unsigned short* dB0b= &sB[1][wid<<9];

  // A fragment row indices (kt-independent)
  int am[4];
  #pragma unroll
  for (int mi = 0; mi < 4; ++mi) am[mi] = (wr<<6) + (mi<<4) + (lane&15);
  // B fragment read offsets
  int boff[4];
  #pragma unroll
  for (int ni = 0; ni < 4; ++ni){
    int c = (wc<<6) + (ni<<4) + (lane&15);
    boff[ni] = (c<<5) + (((lane>>4) ^ ((c>>1)&3))<<3);
  }

  f32x4 acc[4][4];
  #pragma unroll
  for (int mi = 0; mi < 4; ++mi)
    #pragma unroll
    for (int ni = 0; ni < 4; ++ni) acc[mi][ni] = (f32x4){0.f,0.f,0.f,0.f};

  // prologue: stage B step 0 into buffer 0
  gl16(bSU, dB0);
  __syncthreads();

  #pragma unroll 2
  for (int kt = 0; kt < 10; ++kt){
    int cur = kt & 1;
    if (kt < 9){                         // prefetch B step kt+1 into other buffer
      int k1o = (kt+1) << 5;
      const unsigned short* bs = (kt+1 < 8) ? (bSU + k1o) : (bSS + ((kt+1-8) << 5));
      gl16(bs, cur ? dB0 : dB0b);
    }
    int q = (kt<<2) + (lane>>4);
    const unsigned short* Ab = wkeh + ((size_t)q<<11);
    const unsigned short* Bb = sB[cur];
    bf16x8 af[4], bfv[4];
    #pragma unroll
    for (int mi = 0; mi < 4; ++mi) af[mi] = *(const bf16x8*)(Ab + (am[mi]<<3));
    #pragma unroll
    for (int ni = 0; ni < 4; ++ni) bfv[ni] = *(const bf16x8*)(Bb + boff[ni]);
    #pragma unroll
    for (int mi = 0; mi < 4; ++mi)
      #pragma unroll
      for (int ni = 0; ni < 4; ++ni)
        acc[mi][ni] = __builtin_amdgcn_mfma_f32_16x16x32_bf16(af[mi], bfv[ni], acc[mi][ni], 0,0,0);
    __syncthreads();                     // drains prefetch + protects buffer reuse
  }

  // epilogue: per-wave LDS transpose (col-major 72-stride), no barriers.
  unsigned short* wbase = sW[wid];
  int col16 = lane & 15;                 // staging column within 16-col group
  int rcol  = lane >> 2;                 // copy-out column (0..15)
  int rseg  = lane & 3;                  // copy-out 16-m segment
  #pragma unroll
  for (int ni = 0; ni < 4; ++ni){
    #pragma unroll
    for (int mi = 0; mi < 4; ++mi){
      int mloc = (mi<<4) + ((lane>>4)<<2);
      ushort4 o;
      #pragma unroll
      for (int rr = 0; rr < 4; ++rr)
        ((unsigned short*)&o)[rr] = f2b(gelu_t(acc[mi][ni][rr]));
      *(ushort4*)&wbase[col16*72 + mloc] = o;
    }
    int bcO = (nt<<7) + (wc<<6) + (ni<<4) + rcol;
    unsigned short* op = uy + (((size_t)((bcO>>5)*HH + h))<<13) + ((bcO&31)<<8)
                       + (wr<<6) + (rseg<<4);
    uint4 va = *(const uint4*)&wbase[rcol*72 + (rseg<<4)];
    uint4 vb = *(const uint4*)&wbase[rcol*72 + (rseg<<4) + 8];
    *(uint4*)op       = va;
    *(uint4*)(op + 8) = vb;
  }
}

// ---------------- K3: GLU GEMM via MFMA + fused max-pool ----------------
// R12 wave-split version (k3 staging local optimum: 6 restructure attempts
// R3/R4/R6/R13/R22 all regressed vs this scalar-transpose + shared-sA form).
__global__ __launch_bounds__(512) void k3_glu(const unsigned short* __restrict__ y,
                                              const unsigned short* __restrict__ wot,
                                              const float* __restrict__ bo,
                                              float* __restrict__ part){
  __shared__ unsigned short sA[128*64];       // shared by both groups (16 KB)
  __shared__ unsigned short sB[2][128*64];    // per-group (2 x 16 KB)
  __shared__ float smax[2][256];
  int t = threadIdx.x;
  int lane = t & 63, wid = t >> 6;
  int wg = wid >> 2;          // wave-group 0/1
  int wl = wid & 3;           // wave within group
  int bid = blockIdx.x;
  int lb = ((bid & 7) << 8) + (bid >> 3);     // 2048 = 8*256, XCD chunking
  int js2 = lb & 1, mb = (lb >> 1) & 63, b = lb >> 7;
  int js = (js2 << 1) + wg;   // this group's js (0..3)
  f32x4 acc[2][8];
  #pragma unroll
  for (int i = 0; i < 2; ++i)
    #pragma unroll
    for (int j = 0; j < 8; ++j)
      acc[i][j] = (f32x4){0.f,0.f,0.f,0.f};

  for (int kt = 0; kt < 4; ++kt){
    __syncthreads();
    {
      // A: all 512 threads cooperatively transpose the 64h x 128l tile (once)
      int hl = t & 63, g = t >> 6;            // g in 0..7
      const unsigned short* yb = y + (((size_t)(b*HH + (kt<<6) + hl))<<13) + (mb<<7);
      int qh = hl >> 3, hm = hl & 7;
      #pragma unroll
      for (int rep = 0; rep < 2; ++rep){
        int m0 = ((rep<<3) + g) << 3;
        float4 v = *(const float4*)(yb + m0);
        const unsigned short* pv = (const unsigned short*)&v;
        #pragma unroll
        for (int j = 0; j < 8; ++j){
          int m = m0 + j;
          sA[(m<<6) + ((qh ^ (m&7))<<3) + hm] = pv[j];
        }
      }
    }
    {
      // B: each group stages its own js half
      int tt = t & 255;
      #pragma unroll
      for (int p = 0; p < 4; ++p){
        int idx = (p<<8) + tt;
        int row = idx >> 3, sl = idx & 7;
        int ng = (row < 64) ? ((js<<6) + row) : (256 + (js<<6) + row - 64);
        const float4 v = *(const float4*)(wot + (ng<<8) + (kt<<6) + (sl<<3));
        *(float4*)&sB[wg][(row<<6) + ((sl ^ (row&7))<<3)] = v;
      }
    }
    __syncthreads();
    #pragma unroll
    for (int kk = 0; kk < 2; ++kk){
      bf16x8 af[2], bfr[8];
      #pragma unroll
      for (int mi = 0; mi < 2; ++mi){
        int r = (wl<<5) + (mi<<4) + (lane&15);
        int sl = (kk<<2) + (lane>>4);
        af[mi] = *(const bf16x8*)&sA[(r<<6) + ((sl ^ (r&7))<<3)];
      }
      #pragma unroll
      for (int ni = 0; ni < 8; ++ni){
        int r = (ni<<4) + (lane&15);
        int sl = (kk<<2) + (lane>>4);
        bfr[ni] = *(const bf16x8*)&sB[wg][(r<<6) + ((sl ^ (r&7))<<3)];
      }
      #pragma unroll
      for (int ni = 0; ni < 8; ++ni)
        #pragma unroll
        for (int mi = 0; mi < 2; ++mi)
          acc[mi][ni] = __builtin_amdgcn_mfma_f32_16x16x32_bf16(af[mi], bfr[ni], acc[mi][ni], 0, 0, 0);
    }
  }

  float bo1[4], bo2[4];
  #pragma unroll
  for (int ni = 0; ni < 4; ++ni){
    int col = (js<<6) + (ni<<4) + (lane&15);
    bo1[ni] = bo[col]; bo2[ni] = bo[256 + col];
  }
  #pragma unroll
  for (int ni = 0; ni < 4; ++ni){
    float m = -3.4e38f;
    #pragma unroll
    for (int mi = 0; mi < 2; ++mi)
      #pragma unroll
      for (int r = 0; r < 4; ++r){
        float v1 = acc[mi][ni][r] + bo1[ni];
        float v2 = acc[mi][ni+4][r] + bo2[ni];
        float g = v1 * (1.0f/(1.0f + __expf(-v2)));
        m = fmaxf(m, g);
      }
    m = fmaxf(m, __shfl_xor(m, 16));
    m = fmaxf(m, __shfl_xor(m, 32));
    if (lane < 16) smax[wg][(wl<<6) + (ni<<4) + lane] = m;
  }
  __syncthreads();
  if (t < 128){
    int wg2 = t >> 6, tt = t & 63;
    int jso = (js2 << 1) + wg2;
    float m = fmaxf(fmaxf(smax[wg2][tt], smax[wg2][64+tt]),
                    fmaxf(smax[wg2][128+tt], smax[wg2][192+tt]));
    part[(((size_t)b<<6) + mb)*256 + (jso<<6) + tt] = m;
  }
}

// ---------------- K3.5 / K4a / K4b ----------------
__global__ void k35_pool(const float* __restrict__ part, float* __restrict__ pool){
  int b = blockIdx.x, j = threadIdx.x;
  float m = -3.4e38f;
  for (int mb = 0; mb < 64; ++mb)
    m = fmaxf(m, part[(((size_t)b<<6) + mb)*256 + j]);
  pool[(b<<8) + j] = m;
}
__global__ void k4a_fc2(const float* __restrict__ pool, const float* __restrict__ W2,
                        const float* __restrict__ b2, float* __restrict__ f){
  int id = blockIdx.x*256 + threadIdx.x;
  int b = id >> 9, ko = id & 511;
  float s = b2[ko];
  #pragma unroll 8
  for (int hh = 0; hh < 256; ++hh)
    s = fmaf(pool[(b<<8) + hh], W2[hh*512 + ko], s);
  f[id] = s > 0.0f ? s : 0.01f*s;
}
__global__ void k4b_head(const float* __restrict__ f, const float* __restrict__ W3,
                         const float* __restrict__ b3, float* __restrict__ out){
  __shared__ float lg[160];
  int t = threadIdx.x;
  if (t < 160){
    int b = t/10, c = t - 10*b;
    float s = b3[c];
    #pragma unroll 8
    for (int ko = 0; ko < 512; ++ko)
      s = fmaf(f[(b<<9) + ko], W3[ko*10 + c], s);
    lg[t] = s;
    out[t] = s;
  }
  __syncthreads();
  if (t < 10){
    int bi = 0; float bvv = lg[t];
    for (int b2i = 1; b2i < 16; ++b2i){
      float vv = lg[b2i*10 + t];
      if (vv > bvv){ bvv = vv; bi = b2i; }
    }
    out[160 + t] = (float)bi;
  }
}

extern "C" void kernel_launch(void* const* d_in, const int* in_sizes, int n_in,
                              void* d_out, int out_size, void* d_ws, size_t ws_size,
                              hipStream_t stream) {
  const float* x      = (const float*)d_in[0];
  const float* W1     = (const float*)d_in[1];
  const float* b1     = (const float*)d_in[2];
  const float* lng    = (const float*)d_in[3];
  const float* lnb    = (const float*)d_in[4];
  const float* log_dt = (const float*)d_in[5];
  const float* logA   = (const float*)d_in[6];
  const float* Aim    = (const float*)d_in[7];
  const float* Cre    = (const float*)d_in[8];
  const float* Cim    = (const float*)d_in[9];
  const float* Dp     = (const float*)d_in[10];
  const float* Wo     = (const float*)d_in[11];
  const float* bo     = (const float*)d_in[12];
  const float* W2     = (const float*)d_in[13];
  const float* b2     = (const float*)d_in[14];
  const float* W3     = (const float*)d_in[15];
  const float* b3     = (const float*)d_in[16];
  char* wsb = (char*)d_ws;
  unsigned short* u   = (unsigned short*)(wsb + U_OFF);
  float* prm          = (float*)(wsb + PRM_OFF);
  unsigned short* wke = (unsigned short*)(wsb + WKE_OFF);
  unsigned short* fb  = (unsigned short*)(wsb + F_OFF);
  unsigned short* sbh = (unsigned short*)(wsb + SBH_OFF);
  unsigned short* w1t = (unsigned short*)(wsb + W1T_OFF);
  unsigned short* wot = (unsigned short*)(wsb + WOT_OFF);
  float* part         = (float*)(wsb + PART_OFF);
  float* pool         = (float*)(wsb + POOL_OFF);
  float* fbuf         = (float*)(wsb + FC_OFF);
  float* out          = (float*)d_out;

  kp_all   <<<dim3(10912),dim3(256), 0, stream>>>(log_dt, logA, Aim, Cre, Cim, prm,
                                                  Wo, wot, W1, w1t, wke, fb);
  kp_khw   <<<dim3(256),  dim3(256), 0, stream>>>(prm, Dp, wke);
  k1_fc1_ln<<<dim3(2048), dim3(512), 0, stream>>>(x, w1t, b1, lng, lnb, u);
  k2a_states<<<dim3(1024),dim3(256), 0, stream>>>(u, fb, prm, sbh);
  k2c_emit <<<dim3(1024), dim3(512), 0, stream>>>(u, wke, sbh);
  k3_glu   <<<dim3(2048), dim3(512), 0, stream>>>(u, wot, bo, part);
  k35_pool <<<dim3(16),   dim3(256), 0, stream>>>(part, pool);
  k4a_fc2  <<<dim3(32),   dim3(256), 0, stream>>>(pool, W2, b2, fbuf);
  k4b_head <<<dim3(1),    dim3(256), 0, stream>>>(fbuf, W3, b3, out);
}